// Round 3
// baseline (632.878 us; speedup 1.0000x reference)
//
#include <hip/hip_runtime.h>
#include <math.h>

#define T_   50
#define B_   2048
#define NS_  12
#define NC_  4
#define NSC_ 16
#define LDC  20          // padded LDS row stride (riccati kernel only)
#define TAUS_STRIDE 808  // per-alpha stride for tau trajectories (50*16=800, +8 pad)

__device__ __forceinline__ float dot4f(const float4 a, const float4 b) {
    return a.x*b.x + a.y*b.y + a.z*b.z + a.w*b.w;
}
__device__ __forceinline__ void axpy4(float4& acc, float s, const float4 v) {
    acc.x += s*v.x; acc.y += s*v.y; acc.z += s*v.z; acc.w += s*v.w;
}

// Wave-local sync (single-wave ordering). Drains lgkmcnt only; vmcnt stays
// in flight. 0xC07F = vmcnt(63) expcnt(7) lgkmcnt(0).
__device__ __forceinline__ void wsync() {
    __builtin_amdgcn_wave_barrier();
    __builtin_amdgcn_s_waitcnt(0xC07F);
    __builtin_amdgcn_wave_barrier();
}

// Cross-wave barrier: drains LDS (lgkmcnt) but NOT vmcnt, so prefetched
// global loads survive the barrier. Fused in one asm volatile + "memory"
// clobber: nothing reorders between waitcnt and barrier.
__device__ __forceinline__ void bsync() {
    asm volatile("s_waitcnt lgkmcnt(0)\n\ts_barrier" ::: "memory");
}

// ---------------------------------------------------------------------------
// Kernel 1: backward Riccati recursion. One 64-lane wave per batch element.
// (unchanged this round — isolate the rollout change for attribution)
// ---------------------------------------------------------------------------
struct RicPref { float4 rC, rAux; };

__device__ __forceinline__ RicPref ric_load(
    const float* Cg, const float* cg, const float* Fg, const float* fg,
    int t, int b, int lane)
{
    RicPref p;
    const size_t base = (size_t)t * B_ + b;
    p.rC = ((const float4*)(Cg + base*256))[lane];
    if (lane < 48)      p.rAux = ((const float4*)(Fg + base*192))[lane];
    else if (lane < 52) p.rAux = ((const float4*)(cg + base*16))[lane-48];
    else if (lane < 55) p.rAux = ((const float4*)(fg + base*12))[lane-52];
    return p;
}

__global__ __launch_bounds__(64) void riccati_kernel(
    const float* __restrict__ Cg, const float* __restrict__ cg,
    const float* __restrict__ Fg, const float* __restrict__ fg,
    float* __restrict__ Kk)
{
    const int b    = blockIdx.x;
    const int lane = threadIdx.x;

    __shared__ __align__(16) float sV[144];      // V  12x12 (stride 12)
    __shared__ __align__(16) float sv[12];
    __shared__ __align__(16) float sF[12*LDC];   // F  12x16 (stride 20)
    __shared__ __align__(16) float sC[16*LDC];   // C  16x16 (stride 20)
    __shared__ __align__(16) float sc[16];
    __shared__ __align__(16) float sf[12];
    __shared__ __align__(16) float sP[12*LDC];   // P = V*F  12x16
    __shared__ __align__(16) float sQ[16*LDC];   // Q 16x16
    __shared__ __align__(16) float sq[16];
    __shared__ __align__(16) float stmp[12];     // V f + v
    __shared__ __align__(16) float sK[48];       // K 4x12 row-major
    __shared__ __align__(16) float skk[4];
    __shared__ __align__(16) float sM[144];      // M = K^T Qux  12x12 (stride 12)

    for (int i = lane; i < 144; i += 64) sV[i] = 0.f;
    if (lane < 12) sv[lane] = 0.f;

    RicPref cur = ric_load(Cg, cg, Fg, fg, T_-1, b, lane);
    wsync();

    for (int t = T_ - 1; t >= 0; --t) {
        const size_t base = (size_t)t * B_ + b;

        wsync();   // WAR: prior phases' LDS reads complete before overwrite
        {
            const int row = lane >> 2, ch = (lane & 3) << 2;
            *(float4*)(sC + row*LDC + ch) = cur.rC;
            if (lane < 48)      *(float4*)(sF + row*LDC + ch) = cur.rAux;
            else if (lane < 52) ((float4*)sc)[lane-48] = cur.rAux;
            else if (lane < 55) ((float4*)sf)[lane-52] = cur.rAux;
        }
        RicPref nxt = ric_load(Cg, cg, Fg, fg, (t > 0) ? t-1 : 0, b, lane);
        wsync();

        // ---- P = V * F (12x16); tmp = V f + v ----
        if (lane < 48) {
            const int k = lane >> 2, jc = (lane & 3) << 2;
            float4 acc = make_float4(0.f,0.f,0.f,0.f);
            #pragma unroll
            for (int l = 0; l < 12; ++l) {
                axpy4(acc, sV[k*12 + l], *(const float4*)(sF + l*LDC + jc));
            }
            *(float4*)(sP + k*LDC + jc) = acc;
        } else if (lane < 60) {
            const int k = lane - 48;
            float acc = sv[k];
            #pragma unroll
            for (int l = 0; l < 12; ++l) acc += sV[k*12 + l] * sf[l];
            stmp[k] = acc;
        }
        wsync();

        // ---- Q = C + F^T P (16x16); q = c + F^T tmp ----
        {
            const int i = lane >> 2, jc = (lane & 3) << 2;
            float4 acc = *(const float4*)(sC + i*LDC + jc);
            #pragma unroll
            for (int k = 0; k < 12; ++k) {
                axpy4(acc, sF[k*LDC + i], *(const float4*)(sP + k*LDC + jc));
            }
            *(float4*)(sQ + i*LDC + jc) = acc;
        }
        if (lane < 16) {
            float acc = sc[lane];
            #pragma unroll
            for (int k = 0; k < 12; ++k) acc += sF[k*LDC + lane] * stmp[k];
            sq[lane] = acc;
        }
        wsync();

        // ---- solve Quu * sol = [Qux | qu] via redundant 4x4 Cholesky ----
        {
            const float* Qu = sQ + 12*LDC + 12;
            const float a00=Qu[0],      a01=Qu[1],      a02=Qu[2],      a03=Qu[3];
            const float a11=Qu[LDC+1],  a12=Qu[LDC+2],  a13=Qu[LDC+3];
            const float a22=Qu[2*LDC+2],a23=Qu[2*LDC+3],a33=Qu[3*LDC+3];
            const float l00 = sqrtf(a00), i00 = 1.f/l00;
            const float l10 = a01*i00, l20 = a02*i00, l30 = a03*i00;
            const float l11 = sqrtf(a11 - l10*l10), i11 = 1.f/l11;
            const float l21 = (a12 - l20*l10)*i11;
            const float l31 = (a13 - l30*l10)*i11;
            const float l22 = sqrtf(a22 - l20*l20 - l21*l21), i22 = 1.f/l22;
            const float l32 = (a23 - l30*l20 - l31*l21)*i22;
            const float l33 = sqrtf(a33 - l30*l30 - l31*l31 - l32*l32), i33 = 1.f/l33;
            if (lane < 13) {
                float r0, r1, r2, r3;
                if (lane < 12) {
                    r0 = sQ[12*LDC + lane]; r1 = sQ[13*LDC + lane];
                    r2 = sQ[14*LDC + lane]; r3 = sQ[15*LDC + lane];
                } else {
                    r0 = sq[12]; r1 = sq[13]; r2 = sq[14]; r3 = sq[15];
                }
                const float y0 = r0*i00;
                const float y1 = (r1 - l10*y0)*i11;
                const float y2 = (r2 - l20*y0 - l21*y1)*i22;
                const float y3 = (r3 - l30*y0 - l31*y1 - l32*y2)*i33;
                const float z3 = y3*i33;
                const float z2 = (y2 - l32*z3)*i22;
                const float z1 = (y1 - l21*z2 - l31*z3)*i11;
                const float z0 = (y0 - l10*z1 - l20*z2 - l30*z3)*i00;
                if (lane < 12) {
                    sK[0*12+lane] = -z0; sK[1*12+lane] = -z1;
                    sK[2*12+lane] = -z2; sK[3*12+lane] = -z3;
                } else {
                    skk[0] = -z0; skk[1] = -z1; skk[2] = -z2; skk[3] = -z3;
                }
            }
        }
        wsync();

        // ---- emit K,kk; M = K^T Qux; v' = qx + Qxu kk ----
        if (lane < 52) {
            (Kk + base*52)[lane] = (lane < 48) ? sK[lane] : skk[lane-48];
        }
        if (lane < 36) {
            const int i = lane / 3, jc = (lane % 3) << 2;
            float4 acc = make_float4(0.f,0.f,0.f,0.f);
            #pragma unroll
            for (int m = 0; m < 4; ++m) {
                axpy4(acc, sK[m*12 + i], *(const float4*)(sQ + (12+m)*LDC + jc));
            }
            *(float4*)(sM + i*12 + jc) = acc;
        } else if (lane < 48) {
            const int i = lane - 36;
            float acc = sq[i];
            #pragma unroll
            for (int m = 0; m < 4; ++m) acc += sQ[i*LDC + 12 + m] * skk[m];
            sv[i] = acc;
        }
        wsync();

        // ---- V' = Qxx + 0.5(M + M^T) ----
        if (lane < 36) {
            const int i = lane / 3, jc = (lane % 3) << 2;
            const float4 q  = *(const float4*)(sQ + i*LDC + jc);
            const float4 m1 = *(const float4*)(sM + i*12 + jc);
            const float t0 = sM[(jc+0)*12 + i];
            const float t1 = sM[(jc+1)*12 + i];
            const float t2 = sM[(jc+2)*12 + i];
            const float t3 = sM[(jc+3)*12 + i];
            float4 r;
            r.x = q.x + 0.5f*(m1.x + t0);
            r.y = q.y + 0.5f*(m1.y + t1);
            r.z = q.z + 0.5f*(m1.z + t2);
            r.w = q.w + 0.5f*(m1.w + t3);
            *(float4*)(sV + i*12 + jc) = r;
        }
        cur = nxt;
    }
}

// ---------------------------------------------------------------------------
// Kernel 2: rollout, v3. Two waves/block, but C/F/K rows live in per-lane
// REGISTERS loaded directly from global (uniform branch-free load sequence,
// ping-pong double-buffered via 2x-unrolled t-loop). LDS holds only the tau
// trajectory (alpha-group broadcast reads) + unom. This removes ~60% of the
// per-step LDS traffic (the all-distinct-address row reads) that bound v1/v2.
// ---------------------------------------------------------------------------
struct RollPref { float4 row[4]; float4 aux[4]; float s0, s1; };

__global__ __launch_bounds__(128, 4) void rollout_kernel(
    const float* __restrict__ x0g, const float* __restrict__ Cg,
    const float* __restrict__ cg,  const float* __restrict__ Fg,
    const float* __restrict__ fg,  const float* __restrict__ Kk,
    float* __restrict__ outg)
{
    const int b    = blockIdx.x;
    const int tid  = threadIdx.x;
    const int wave = tid >> 6;
    const int lane = tid & 63;

    __shared__ __align__(16) float staus[5*TAUS_STRIDE]; // [a][t][16]
    __shared__ __align__(16) float sunom[T_*NC_];        // [t][4]
    __shared__ __align__(16) float sx0[12];
    __shared__ float scost[5];
    __shared__ int   sbest;

    // ---------------- per-lane task constants (loop-invariant) ----------------
    // task = wave*64+lane: 0..79 cost (a=task>>4, i=task&15); 80..127 x_next
    // (v=task-80, a=v/12, i=v%12). wave0 = tasks 0..63 (all cost).
    const int  task    = wave*64 + lane;
    const bool is_cost = task < 80;
    int a1, i1;
    if (is_cost) { a1 = task >> 4; i1 = task & 15; }
    else { const int v = task - 80; a1 = v / 12; i1 = v - a1*12; }
    float* taub1 = staus + a1*TAUS_STRIDE;

    // wave0 tail: x_next alpha4, row iT (compute guarded lane<12; loads uniform)
    const int iT = (lane < 12) ? lane : 11;
    float* taubT = staus + 4*TAUS_STRIDE;

    // wave1 u-phase: a=lane>>2 (0..4), i=lane&3 (compute guarded lane<20)
    const int   aA  = (lane < 20) ? (lane >> 2) : 0;
    const int   iA  = lane & 3;
    const float alA = ldexpf(1.0f, -aA);   // 0.5^a

    // ---- branch-free global row/scalar bases (floats) + per-step strides ----
    const float *rowB, *auxB, *s0B, *s1B;
    int rowS, auxS, s0S, s1S;
    if (wave == 0) {
        rowB = Cg + (size_t)b*256 + i1*16;  rowS = B_*256;   // C row i1
        s0B  = cg + (size_t)b*16  + i1;     s0S  = B_*16;    // c[i1]
        auxB = Fg + (size_t)b*192 + iT*16;  auxS = B_*192;   // F row iT (tail)
        s1B  = fg + (size_t)b*12  + iT;     s1S  = B_*12;    // f[iT]
    } else {
        if (is_cost) { rowB = Cg + (size_t)b*256 + i1*16; rowS = B_*256;
                       s0B  = cg + (size_t)b*16  + i1;    s0S  = B_*16; }
        else         { rowB = Fg + (size_t)b*192 + i1*16; rowS = B_*192;
                       s0B  = fg + (size_t)b*12  + i1;    s0S  = B_*12; }
        auxB = Kk + (size_t)b*52 + iA*12;   auxS = B_*52;    // K row iA (aux[3] = kk area, valid)
        s1B  = Kk + (size_t)b*52 + 48 + iA; s1S  = B_*52;    // kk[iA]
    }

    auto load_pref = [&](RollPref& p, int tn) {
        const float* rp = rowB + tn*rowS;
        p.row[0] = *(const float4*)(rp);
        p.row[1] = *(const float4*)(rp + 4);
        p.row[2] = *(const float4*)(rp + 8);
        p.row[3] = *(const float4*)(rp + 12);
        const float* ap = auxB + tn*auxS;
        p.aux[0] = *(const float4*)(ap);
        p.aux[1] = *(const float4*)(ap + 4);
        p.aux[2] = *(const float4*)(ap + 8);
        p.aux[3] = *(const float4*)(ap + 12);
        p.s0 = *(s0B + tn*s0S);
        p.s1 = *(s1B + tn*s1S);
    };

    // one rollout step; cur = data(t), issues loads(t+1) into nxt
    auto do_step = [&](RollPref& cur, RollPref& nxt, int t, int toff, float& ca) {
        bsync();                               // B1: x(t) published
        const int tn = (t+1 < T_) ? t+1 : 0;
        load_pref(nxt, tn);                    // prefetch t+1 (vmcnt stays in flight)

        // u-phase (wave1, lanes<20): u(t) from K(t) regs + x(t) LDS
        if (wave == 1 && lane < 20) {
            const float* xp = staus + aA*TAUS_STRIDE + toff;
            float ulqr = dot4f(cur.aux[0], *(const float4*)(xp))
                       + dot4f(cur.aux[1], *(const float4*)(xp+4))
                       + dot4f(cur.aux[2], *(const float4*)(xp+8))
                       + cur.s1;
            float u = (1.f - alA)*sunom[t*4 + iA] + alA*ulqr;
            u = fminf(1.f, fmaxf(-1.f, u));
            staus[aA*TAUS_STRIDE + toff + 12 + iA] = u;
        }

        // pre-B2 partial: x-part of the dot (x(t) available since B1)
        const float* tp = taub1 + toff;
        float acc = is_cost ? 0.f : cur.s0;    // x_next starts at f_i (order-exact)
        acc += dot4f(cur.row[0], *(const float4*)(tp));
        acc += dot4f(cur.row[1], *(const float4*)(tp+4));
        acc += dot4f(cur.row[2], *(const float4*)(tp+8));

        float accT = 0.f;
        if (wave == 0 && lane < 12) {          // tail pre-partial (alpha4 x_next)
            const float* tq = taubT + toff;
            accT = cur.s1;
            accT += dot4f(cur.aux[0], *(const float4*)(tq));
            accT += dot4f(cur.aux[1], *(const float4*)(tq+4));
            accT += dot4f(cur.aux[2], *(const float4*)(tq+8));
        }

        bsync();                               // B2: u(t) published

        acc += dot4f(cur.row[3], *(const float4*)(taub1 + toff + 12));
        const bool tnl = (t != T_-1);
        if (is_cost) {
            const float ti = taub1[toff + i1];
            ca += (0.5f*acc + cur.s0) * ti;
        } else if (tnl) {
            taub1[toff + 16 + i1] = acc;       // x(t+1)
        }
        if (wave == 0 && lane < 12 && tnl) {
            accT += dot4f(cur.aux[3], *(const float4*)(taubT + toff + 12));
            taubT[toff + 16 + iT] = accT;
        }
    };

    // ---------------- prologue ----------------
    for (int i = tid; i < T_*NC_; i += 128) sunom[i] = 0.f;
    if (tid < 3) ((float4*)sx0)[tid] = ((const float4*)(x0g + (size_t)b*12))[tid];

    RollPref R0, R1;
    load_pref(R0, 0);
    bsync();

    for (int iter = 0; iter < 3; ++iter) {
        // x(0) = x0 into row 0 of every alpha's trajectory
        if (tid < 15) {
            const int a = tid / 3, ch = (tid % 3) << 2;
            *(float4*)(staus + a*TAUS_STRIDE + ch) = *(const float4*)(sx0 + ch);
        }
        float ca = 0.f;   // wave0: alphas 0-3 (16-lane groups); wave1 lanes<16: alpha4

        for (int t = 0; t < T_; t += 2) {      // 2x unroll: register ping-pong
            do_step(R0, R1, t,   t*16,     ca);
            do_step(R1, R0, t+1, t*16+16,  ca);
        }
        // after 50 (even) steps, R0 again holds t=0 data for the next iter

        // ---- reduce costs (16-lane groups), select best alpha ----
        #pragma unroll
        for (int off = 1; off < 16; off <<= 1) ca += __shfl_xor(ca, off, 16);
        if (wave == 0) { if ((lane & 15) == 0) scost[lane >> 4] = ca; }
        else if (lane == 0) scost[4] = ca;
        bsync();
        if (tid == 0) {
            int bi = 0; float bc = scost[0];
            #pragma unroll
            for (int a = 1; a < 5; ++a) {
                if (scost[a] < bc) { bc = scost[a]; bi = a; }  // first-min = jnp.argmin
            }
            sbest = bi;
        }
        bsync();
        const int best = sbest;

        // ---- u_nom <- best trajectory's u; final iter: write taus out ----
        for (int idx = tid; idx < T_*NC_; idx += 128) {
            const int tt = idx >> 2, i = idx & 3;
            sunom[idx] = staus[best*TAUS_STRIDE + tt*16 + 12 + i];
        }
        if (iter == 2) {
            for (int idx = tid; idx < T_*NSC_; idx += 128) {
                const int tt = idx >> 4, j = idx & 15;
                outg[((size_t)tt*B_ + b)*16 + j] = staus[best*TAUS_STRIDE + tt*16 + j];
            }
        }
        bsync();
    } // iter
}

extern "C" void kernel_launch(void* const* d_in, const int* in_sizes, int n_in,
                              void* d_out, int out_size, void* d_ws, size_t ws_size,
                              hipStream_t stream) {
    const float* x0 = (const float*)d_in[0];
    const float* C  = (const float*)d_in[1];
    const float* c  = (const float*)d_in[2];
    const float* F  = (const float*)d_in[3];
    const float* f  = (const float*)d_in[4];
    float* out = (float*)d_out;
    float* Kk  = (float*)d_ws;   // needs 50*2048*52*4 = 21.3 MB

    riccati_kernel<<<B_, 64, 0, stream>>>(C, c, F, f, Kk);
    rollout_kernel<<<B_, 128, 0, stream>>>(x0, C, c, F, f, Kk, out);
}

// Round 4
// 443.791 us; speedup vs baseline: 1.4261x; 1.4261x over previous
//
#include <hip/hip_runtime.h>
#include <math.h>

#define T_   50
#define B_   2048
#define NS_  12
#define NC_  4
#define NSC_ 16
#define LDC  20          // padded LDS row stride for 16-wide matrices (bank decorrelation)
#define TAUS_STRIDE 808  // per-alpha stride for tau trajectories (50*16=800, +8 pad)

__device__ __forceinline__ float dot4f(const float4 a, const float4 b) {
    return a.x*b.x + a.y*b.y + a.z*b.z + a.w*b.w;
}
__device__ __forceinline__ void axpy4(float4& acc, float s, const float4 v) {
    acc.x += s*v.x; acc.y += s*v.y; acc.z += s*v.z; acc.w += s*v.w;
}

// Wave-local sync for single-wave phases. Orders LDS traffic
// (s_waitcnt lgkmcnt(0)) WITHOUT draining vmcnt, so prefetched global loads
// stay in flight across compute phases.
// 0xC07F = vmcnt(63) expcnt(7) lgkmcnt(0) in gfx9-lineage encoding.
__device__ __forceinline__ void wsync() {
    __builtin_amdgcn_wave_barrier();
    __builtin_amdgcn_s_waitcnt(0xC07F);
    __builtin_amdgcn_wave_barrier();
}

// Cross-wave barrier (2-wave blocks): drains LDS (lgkmcnt) but NOT vmcnt.
// CRITICAL: built from builtins + clobber-free primitives. An asm barrier
// with a "memory" clobber is treated as a memory access by the backend
// waitcnt pass, which then drains vmcnt(0) before it — silently killing the
// global prefetch pipeline (the Round-1..3 regression). Raw
// __builtin_amdgcn_s_barrier() provably does NOT force a vmcnt drain
// (counted-vmcnt loads verified in flight across barriers). wave_barrier()
// brackets prevent compiler code motion, same as the long-verified wsync().
__device__ __forceinline__ void bsync() {
    __builtin_amdgcn_wave_barrier();
    __builtin_amdgcn_s_waitcnt(0xC07F);   // lgkmcnt(0) only; vmcnt untouched
    __builtin_amdgcn_s_barrier();
    __builtin_amdgcn_wave_barrier();
}

// ---------------------------------------------------------------------------
// Kernel 1: backward Riccati recursion. One 64-lane wave per batch element.
// Register-prefetches (C,F,c,f) for step t-1 while computing step t.
// (unchanged — verified; wsync was always non-draining)
// ---------------------------------------------------------------------------
struct RicPref { float4 rC, rAux; };

__device__ __forceinline__ RicPref ric_load(
    const float* Cg, const float* cg, const float* Fg, const float* fg,
    int t, int b, int lane)
{
    RicPref p;
    const size_t base = (size_t)t * B_ + b;
    p.rC = ((const float4*)(Cg + base*256))[lane];
    if (lane < 48)      p.rAux = ((const float4*)(Fg + base*192))[lane];
    else if (lane < 52) p.rAux = ((const float4*)(cg + base*16))[lane-48];
    else if (lane < 55) p.rAux = ((const float4*)(fg + base*12))[lane-52];
    return p;
}

__global__ __launch_bounds__(64) void riccati_kernel(
    const float* __restrict__ Cg, const float* __restrict__ cg,
    const float* __restrict__ Fg, const float* __restrict__ fg,
    float* __restrict__ Kk)
{
    const int b    = blockIdx.x;
    const int lane = threadIdx.x;

    __shared__ __align__(16) float sV[144];      // V  12x12 (stride 12)
    __shared__ __align__(16) float sv[12];
    __shared__ __align__(16) float sF[12*LDC];   // F  12x16 (stride 20)
    __shared__ __align__(16) float sC[16*LDC];   // C  16x16 (stride 20)
    __shared__ __align__(16) float sc[16];
    __shared__ __align__(16) float sf[12];
    __shared__ __align__(16) float sP[12*LDC];   // P = V*F  12x16
    __shared__ __align__(16) float sQ[16*LDC];   // Q 16x16
    __shared__ __align__(16) float sq[16];
    __shared__ __align__(16) float stmp[12];     // V f + v
    __shared__ __align__(16) float sK[48];       // K 4x12 row-major
    __shared__ __align__(16) float skk[4];
    __shared__ __align__(16) float sM[144];      // M = K^T Qux  12x12 (stride 12)

    for (int i = lane; i < 144; i += 64) sV[i] = 0.f;
    if (lane < 12) sv[lane] = 0.f;

    RicPref cur = ric_load(Cg, cg, Fg, fg, T_-1, b, lane);
    wsync();

    for (int t = T_ - 1; t >= 0; --t) {
        const size_t base = (size_t)t * B_ + b;

        // ---- stage current step's data from prefetch registers ----
        wsync();   // WAR: prior phases' LDS reads complete before overwrite
        {
            const int row = lane >> 2, ch = (lane & 3) << 2;
            *(float4*)(sC + row*LDC + ch) = cur.rC;
            if (lane < 48)      *(float4*)(sF + row*LDC + ch) = cur.rAux;
            else if (lane < 52) ((float4*)sc)[lane-48] = cur.rAux;
            else if (lane < 55) ((float4*)sf)[lane-52] = cur.rAux;
        }
        RicPref nxt = ric_load(Cg, cg, Fg, fg, (t > 0) ? t-1 : 0, b, lane);
        wsync();

        // ---- P = V * F (12x16); tmp = V f + v ----
        if (lane < 48) {
            const int k = lane >> 2, jc = (lane & 3) << 2;
            float4 acc = make_float4(0.f,0.f,0.f,0.f);
            #pragma unroll
            for (int l = 0; l < 12; ++l) {
                axpy4(acc, sV[k*12 + l], *(const float4*)(sF + l*LDC + jc));
            }
            *(float4*)(sP + k*LDC + jc) = acc;
        } else if (lane < 60) {
            const int k = lane - 48;
            float acc = sv[k];
            #pragma unroll
            for (int l = 0; l < 12; ++l) acc += sV[k*12 + l] * sf[l];
            stmp[k] = acc;
        }
        wsync();

        // ---- Q = C + F^T P (16x16); q = c + F^T tmp ----
        {
            const int i = lane >> 2, jc = (lane & 3) << 2;
            float4 acc = *(const float4*)(sC + i*LDC + jc);
            #pragma unroll
            for (int k = 0; k < 12; ++k) {
                axpy4(acc, sF[k*LDC + i], *(const float4*)(sP + k*LDC + jc));
            }
            *(float4*)(sQ + i*LDC + jc) = acc;
        }
        if (lane < 16) {
            float acc = sc[lane];
            #pragma unroll
            for (int k = 0; k < 12; ++k) acc += sF[k*LDC + lane] * stmp[k];
            sq[lane] = acc;
        }
        wsync();

        // ---- solve Quu * sol = [Qux | qu] via redundant 4x4 Cholesky ----
        {
            const float* Qu = sQ + 12*LDC + 12;
            const float a00=Qu[0],      a01=Qu[1],      a02=Qu[2],      a03=Qu[3];
            const float a11=Qu[LDC+1],  a12=Qu[LDC+2],  a13=Qu[LDC+3];
            const float a22=Qu[2*LDC+2],a23=Qu[2*LDC+3],a33=Qu[3*LDC+3];
            const float l00 = sqrtf(a00), i00 = 1.f/l00;
            const float l10 = a01*i00, l20 = a02*i00, l30 = a03*i00;
            const float l11 = sqrtf(a11 - l10*l10), i11 = 1.f/l11;
            const float l21 = (a12 - l20*l10)*i11;
            const float l31 = (a13 - l30*l10)*i11;
            const float l22 = sqrtf(a22 - l20*l20 - l21*l21), i22 = 1.f/l22;
            const float l32 = (a23 - l30*l20 - l31*l21)*i22;
            const float l33 = sqrtf(a33 - l30*l30 - l31*l31 - l32*l32), i33 = 1.f/l33;
            if (lane < 13) {   // one RHS column per lane
                float r0, r1, r2, r3;
                if (lane < 12) {
                    r0 = sQ[12*LDC + lane]; r1 = sQ[13*LDC + lane];
                    r2 = sQ[14*LDC + lane]; r3 = sQ[15*LDC + lane];
                } else {
                    r0 = sq[12]; r1 = sq[13]; r2 = sq[14]; r3 = sq[15];
                }
                const float y0 = r0*i00;
                const float y1 = (r1 - l10*y0)*i11;
                const float y2 = (r2 - l20*y0 - l21*y1)*i22;
                const float y3 = (r3 - l30*y0 - l31*y1 - l32*y2)*i33;
                const float z3 = y3*i33;
                const float z2 = (y2 - l32*z3)*i22;
                const float z1 = (y1 - l21*z2 - l31*z3)*i11;
                const float z0 = (y0 - l10*z1 - l20*z2 - l30*z3)*i00;
                if (lane < 12) {
                    sK[0*12+lane] = -z0; sK[1*12+lane] = -z1;
                    sK[2*12+lane] = -z2; sK[3*12+lane] = -z3;
                } else {
                    skk[0] = -z0; skk[1] = -z1; skk[2] = -z2; skk[3] = -z3;
                }
            }
        }
        wsync();

        // ---- emit K,kk; M = K^T Qux; v' = qx + Qxu kk ----
        if (lane < 52) {
            (Kk + base*52)[lane] = (lane < 48) ? sK[lane] : skk[lane-48];
        }
        if (lane < 36) {
            const int i = lane / 3, jc = (lane % 3) << 2;
            float4 acc = make_float4(0.f,0.f,0.f,0.f);
            #pragma unroll
            for (int m = 0; m < 4; ++m) {
                axpy4(acc, sK[m*12 + i], *(const float4*)(sQ + (12+m)*LDC + jc));
            }
            *(float4*)(sM + i*12 + jc) = acc;
        } else if (lane < 48) {
            const int i = lane - 36;
            float acc = sq[i];
            #pragma unroll
            for (int m = 0; m < 4; ++m) acc += sQ[i*LDC + 12 + m] * skk[m];
            sv[i] = acc;   // v' (no readers of sv until next t's phase 1)
        }
        wsync();

        // ---- V' = Qxx + 0.5(M + M^T)  (matches reference symmetrization) ----
        if (lane < 36) {
            const int i = lane / 3, jc = (lane % 3) << 2;
            const float4 q  = *(const float4*)(sQ + i*LDC + jc);
            const float4 m1 = *(const float4*)(sM + i*12 + jc);
            const float t0 = sM[(jc+0)*12 + i];
            const float t1 = sM[(jc+1)*12 + i];
            const float t2 = sM[(jc+2)*12 + i];
            const float t3 = sM[(jc+3)*12 + i];
            float4 r;
            r.x = q.x + 0.5f*(m1.x + t0);
            r.y = q.y + 0.5f*(m1.y + t1);
            r.z = q.z + 0.5f*(m1.z + t2);
            r.w = q.w + 0.5f*(m1.w + t3);
            *(float4*)(sV + i*12 + jc) = r;
        }
        cur = nxt;
        // loop-top wsync orders V' writes vs next step's P reads
    }
}

// ---------------------------------------------------------------------------
// Kernel 2: 3 LQR iterations of 5-alpha forward rollout + line-search select.
// v4 = v2 structure (verified passing) with the non-draining bsync.
//   Two 64-lane waves per batch element; x_next written directly into the
//   staus trajectory; 140 dot-16 tasks packed across 128 lanes; 2
//   lgkmcnt-only barriers per step — global prefetch now genuinely stays
//   in flight across them.
// ---------------------------------------------------------------------------
struct RollAux { float4 r1, r2; };

__device__ __forceinline__ RollAux aux_load(
    const float* cg, const float* Fg, const float* fg, const float* Kk,
    int t, int b, int lane)
{
    RollAux p;
    const size_t base = (size_t)t * B_ + b;
    if (lane < 48)      p.r1 = ((const float4*)(Fg + base*192))[lane];
    else if (lane < 61) p.r1 = ((const float4*)(Kk + base*52))[lane-48];
    else                p.r1 = ((const float4*)(cg + base*16))[lane-61];
    if (lane == 0)      p.r2 = ((const float4*)(cg + base*16))[3];
    else if (lane < 4)  p.r2 = ((const float4*)(fg + base*12))[lane-1];
    return p;
}

__global__ __launch_bounds__(128, 4) void rollout_kernel(
    const float* __restrict__ x0g, const float* __restrict__ Cg,
    const float* __restrict__ cg,  const float* __restrict__ Fg,
    const float* __restrict__ fg,  const float* __restrict__ Kk,
    float* __restrict__ outg)
{
    const int b    = blockIdx.x;
    const int tid  = threadIdx.x;
    const int wave = tid >> 6;
    const int lane = tid & 63;

    __shared__ __align__(16) float staus[5*TAUS_STRIDE]; // [a][t][16]; rows 0..49 hold tau
    __shared__ __align__(16) float sunom[T_*NC_];        // [t][4]
    __shared__ __align__(16) float sx0[12];
    __shared__ __align__(16) float sC[16*LDC];
    __shared__ __align__(16) float sF[12*LDC];
    __shared__ __align__(16) float sKk[56];
    __shared__ __align__(16) float sc[16];
    __shared__ __align__(16) float sf[12];
    __shared__ float scost[5];
    __shared__ int   sbest;

    // ---------------- loop-invariant per-lane task constants ----------------
    // main BC task = wave*64 + lane:
    //   task 0..79   : cost   (a = task>>4, i = task&15)   [wave0 = pure cost]
    //   task 80..127 : x_next (v = task-80, a = v/12, i = v%12)
    const int  task    = wave*64 + lane;
    const bool is_cost = task < 80;
    int a1, i1;
    if (is_cost) { a1 = task >> 4; i1 = task & 15; }
    else { const int v = task - 80; a1 = v / 12; i1 = v - a1*12; }
    const float* row1  = (is_cost ? (const float*)sC : (const float*)sF) + i1*LDC;
    const float* add1  = (is_cost ? (const float*)sc : (const float*)sf) + i1;
    float*       taub1 = staus + a1*TAUS_STRIDE;

    // wave0 tail: x_next for alpha 4, i = lane (lane<12)
    const int    iT    = (lane < 12) ? lane : 0;
    const float* rowT  = sF + iT*LDC;
    float*       taubT = staus + 4*TAUS_STRIDE;

    // wave1 u-phase constants (lane<20): a = lane>>2 (0..4), i = lane&3
    const int    aA  = (lane < 20) ? (lane >> 2) : 0;
    const int    iA  = lane & 3;
    const float  alA = ldexpf(1.0f, -aA);     // 0.5^a
    const float* KrA = sKk + iA*12;
    float*       tauA = staus + aA*TAUS_STRIDE;

    // ---------------- prologue ----------------
    for (int i = tid; i < T_*NC_; i += 128) sunom[i] = 0.f;
    if (tid < 3) ((float4*)sx0)[tid] = ((const float4*)(x0g + (size_t)b*12))[tid];

    float4  curC;
    RollAux curA;
    if (wave == 0) curC = ((const float4*)(Cg + (size_t)b*256))[lane];
    else           curA = aux_load(cg, Fg, fg, Kk, 0, b, lane);
    bsync();

    for (int iter = 0; iter < 3; ++iter) {
        // x(0) = x0 into row 0 of every alpha's trajectory (disjoint from the
        // u-parts the previous iter-end copies read; B1 of t=0 publishes it).
        if (tid < 15) {
            const int a = tid / 3, ch = (tid % 3) << 2;
            *(float4*)(staus + a*TAUS_STRIDE + ch) = *(const float4*)(sx0 + ch);
        }
        float ca = 0.f;   // cost partial: wave0 lanes = alphas 0-3; wave1 lanes<16 = alpha 4
        int toff = 0;     // t*16

        for (int t = 0; t < T_; ++t) {
            bsync();   // B1: WAR on staged arrays; publishes x(t) (= x_next of t-1)
            if (wave == 0) {
                // stage C(t), then issue prefetch for t+1 (wraps to 0)
                const int row = lane >> 2, ch = (lane & 3) << 2;
                *(float4*)(sC + row*LDC + ch) = curC;
                curC = ((const float4*)(Cg +
                          ((size_t)((t+1 < T_) ? t+1 : 0) * B_ + b)*256))[lane];
            } else {
                // stage F,K,c,f(t), prefetch t+1, then u-phase (needs own sKk: wsync)
                {
                    const int row = lane >> 2, ch = (lane & 3) << 2;
                    if (lane < 48)      *(float4*)(sF + row*LDC + ch) = curA.r1;
                    else if (lane < 61) ((float4*)sKk)[lane-48] = curA.r1;
                    else                ((float4*)sc)[lane-61]  = curA.r1;
                    if (lane == 0)      ((float4*)sc)[3] = curA.r2;
                    else if (lane < 4)  ((float4*)sf)[lane-1] = curA.r2;
                }
                curA = aux_load(cg, Fg, fg, Kk, (t+1 < T_) ? t+1 : 0, b, lane);
                wsync();   // wave-local: sKk/sF stores visible; vmcnt untouched
                if (lane < 20) {   // u for all 5 alphas; x(t) read from staus row t
                    const float* x = tauA + toff;
                    float ulqr = dot4f(*(const float4*)(KrA+0), *(const float4*)(x+0))
                               + dot4f(*(const float4*)(KrA+4), *(const float4*)(x+4))
                               + dot4f(*(const float4*)(KrA+8), *(const float4*)(x+8))
                               + sKk[48 + iA];
                    float u = (1.f - alA)*sunom[t*4 + iA] + alA*ulqr;
                    u = fminf(1.f, fmaxf(-1.f, u));
                    tauA[toff + 12 + iA] = u;
                }
            }
            bsync();   // B2: staged C/F/K/c/f and u(t) visible to both waves

            const bool tnl = (t != T_-1);
            {   // unified cost / x_next body (per-lane precomputed role)
                const float* tau = taub1 + toff;
                const float  av  = add1[0];                 // sc[i] or sf[i]
                float acc = is_cost ? 0.f : av;             // x_next starts at sf[i]
                acc += dot4f(*(const float4*)(row1+ 0), *(const float4*)(tau+ 0));
                acc += dot4f(*(const float4*)(row1+ 4), *(const float4*)(tau+ 4));
                acc += dot4f(*(const float4*)(row1+ 8), *(const float4*)(tau+ 8));
                acc += dot4f(*(const float4*)(row1+12), *(const float4*)(tau+12));
                if (is_cost)  ca += (0.5f*acc + av) * tau[i1];
                else if (tnl) taub1[toff + 16 + i1] = acc;  // x(t+1) -> row t+1
            }
            if (wave == 0 && lane < 12 && tnl) {   // tail: x_next alpha 4
                const float* tau = taubT + toff;
                float acc = sf[iT];
                acc += dot4f(*(const float4*)(rowT+ 0), *(const float4*)(tau+ 0));
                acc += dot4f(*(const float4*)(rowT+ 4), *(const float4*)(tau+ 4));
                acc += dot4f(*(const float4*)(rowT+ 8), *(const float4*)(tau+ 8));
                acc += dot4f(*(const float4*)(rowT+12), *(const float4*)(tau+12));
                taubT[toff + 16 + iT] = acc;
            }
            toff += 16;
        } // t

        // ---- reduce costs (16-lane groups), select best alpha ----
        #pragma unroll
        for (int off = 1; off < 16; off <<= 1) ca += __shfl_xor(ca, off, 16);
        if (wave == 0) { if ((lane & 15) == 0) scost[lane >> 4] = ca; }
        else if (lane == 0) scost[4] = ca;
        bsync();
        if (tid == 0) {
            int bi = 0; float bc = scost[0];
            #pragma unroll
            for (int a = 1; a < 5; ++a) {
                if (scost[a] < bc) { bc = scost[a]; bi = a; }  // first-min: matches jnp.argmin
            }
            sbest = bi;
        }
        bsync();
        const int best = sbest;

        // ---- u_nom <- best trajectory's u; final iter: write taus out ----
        for (int idx = tid; idx < T_*NC_; idx += 128) {
            const int tt = idx >> 2, i = idx & 3;
            sunom[idx] = staus[best*TAUS_STRIDE + tt*16 + 12 + i];
        }
        if (iter == 2) {
            for (int idx = tid; idx < T_*NSC_; idx += 128) {
                const int tt = idx >> 4, j = idx & 15;
                outg[((size_t)tt*B_ + b)*16 + j] = staus[best*TAUS_STRIDE + tt*16 + j];
            }
        }
        bsync();
    } // iter
}

extern "C" void kernel_launch(void* const* d_in, const int* in_sizes, int n_in,
                              void* d_out, int out_size, void* d_ws, size_t ws_size,
                              hipStream_t stream) {
    const float* x0 = (const float*)d_in[0];
    const float* C  = (const float*)d_in[1];
    const float* c  = (const float*)d_in[2];
    const float* F  = (const float*)d_in[3];
    const float* f  = (const float*)d_in[4];
    float* out = (float*)d_out;
    float* Kk  = (float*)d_ws;   // needs 50*2048*52*4 = 21.3 MB

    riccati_kernel<<<B_, 64, 0, stream>>>(C, c, F, f, Kk);
    rollout_kernel<<<B_, 128, 0, stream>>>(x0, C, c, F, f, Kk, out);
}